// Round 1
// baseline (427.018 us; speedup 1.0000x reference)
//
#include <hip/hip_runtime.h>
#include <hip/hip_bf16.h>

// Problem constants (match reference setup_inputs / hyperparams)
constexpr int B  = 4;
constexpr int H  = 544;
constexpr int W  = 960;
constexpr int H2 = 272;   // half-res
constexpr int W2 = 480;
constexpr int NH = B * H2 * W2;     // 522240
constexpr int NF = B * H * W;       // 2088960

// pixel kernel tiling: 32x8 outputs per block, halo 1 -> 34x10 staged
constexpr int TPW = 32, TPH = 8;
constexpr int SW = TPW + 2, SH = TPH + 2;      // 34 x 10
constexpr int NSTAGE = SW * SH;                // 340
constexpr int GX = W / TPW;                    // 30
constexpr int GY = H / TPH;                    // 68
constexpr int NBLK  = GX * GY * B;             // 8160 (k_pix blocks)
constexpr int NBLK2 = (NH + 255) / 256;        // 2040 (k_sgm blocks)

__device__ inline float waveSum(float v) {
  #pragma unroll
  for (int off = 32; off > 0; off >>= 1) v += __shfl_down(v, off, 64);
  return v;
}

// ------- fused pixel kernel: gt + photometric + smoothness + lg/rg downsample -------
__global__ __launch_bounds__(256) void k_pix(const float* __restrict__ pred,
                                             const float* __restrict__ gt,
                                             const float* __restrict__ conf,
                                             const float* __restrict__ occ,
                                             const float* __restrict__ left,
                                             const float* __restrict__ right,
                                             float* __restrict__ lg,
                                             float* __restrict__ rg,
                                             float* __restrict__ partialsA) {
  const int bx = blockIdx.x % GX;
  const int by = (blockIdx.x / GX) % GY;
  const int b  = blockIdx.x / (GX * GY);
  const int x0 = bx * TPW, y0 = by * TPH;
  const int tid = threadIdx.x;

  const float* dispb = pred + (size_t)b * H * W;
  const float* lb = left  + (size_t)b * 3 * H * W;
  const float* rb = right + (size_t)b * 3 * H * W;

  __shared__ float4 L4s[NSTAGE];   // (lv0, lv1, lv2, disp); zeros if OOB
  __shared__ float4 W4s[NSTAGE];   // (wv0, wv1, wv2, 0);    zeros if OOB

  for (int e = tid; e < NSTAGE; e += 256) {
    int r = e / SW, c = e % SW;
    int yy = y0 - 1 + r, xx = x0 - 1 + c;
    float4 l4 = make_float4(0.f, 0.f, 0.f, 0.f);
    float4 w4 = make_float4(0.f, 0.f, 0.f, 0.f);
    if (yy >= 0 && yy < H && xx >= 0 && xx < W) {
      float dv = dispb[yy * W + xx];
      float xsv = (float)xx - dv;
      float xc = fminf(fmaxf(xsv, 0.f), (float)(W - 1));
      float x0f = floorf(xc);
      float w = xc - x0f;
      int x0i = (int)x0f;
      int x1i = min(x0i + 1, W - 1);
      const float* l0 = lb + (size_t)yy * W;
      const float* r0 = rb + (size_t)yy * W;
      l4.x = l0[xx];
      l4.y = l0[(size_t)H * W + xx];
      l4.z = l0[2 * (size_t)H * W + xx];
      l4.w = dv;
      w4.x = r0[x0i] * (1.f - w) + r0[x1i] * w;
      w4.y = r0[(size_t)H * W + x0i] * (1.f - w) + r0[(size_t)H * W + x1i] * w;
      w4.z = r0[2 * (size_t)H * W + x0i] * (1.f - w) + r0[2 * (size_t)H * W + x1i] * w;
    }
    L4s[e] = l4; W4s[e] = w4;
  }
  __syncthreads();

  // ---- lg/rg emission (threads 0..63): 16x4 half-res pixels of this tile ----
  if (tid < 64) {
    int hx = tid & 15, hy = tid >> 4;
    int y2g = (y0 >> 1) + hy, x2g = (x0 >> 1) + hx;
    int i00 = (2 * hy + 1) * SW + (2 * hx + 1);
    float4 a00 = L4s[i00], a01 = L4s[i00 + 1], a10 = L4s[i00 + SW], a11 = L4s[i00 + SW + 1];
    float sl = 0.f;
    sl += a00.x + a01.x + a10.x + a11.x;
    sl += a00.y + a01.y + a10.y + a11.y;
    sl += a00.z + a01.z + a10.z + a11.z;
    float sr = 0.f;
    int yy2 = y0 + 2 * hy, xx2 = x0 + 2 * hx;
    #pragma unroll
    for (int c = 0; c < 3; c++) {
      const float* rp = rb + (size_t)(c * H + yy2) * W + xx2;
      sr += rp[0] + rp[1] + rp[W] + rp[W + 1];
    }
    size_t ho = (size_t)b * (H2 * W2) + (size_t)y2g * W2 + x2g;
    lg[ho] = sl * (1.f / 12.f);
    rg[ho] = sr * (1.f / 12.f);
  }

  float v[6];
  #pragma unroll
  for (int s = 0; s < 6; s++) v[s] = 0.f;

  {
    const int tx = tid & 31, ty = tid >> 5;
    const int x = x0 + tx, y = y0 + ty;
    const size_t gidx = (size_t)b * H * W + (size_t)y * W + x;
    const int ci = (ty + 1) * SW + (tx + 1);

    float sl[3] = {0,0,0}, sw[3] = {0,0,0}, sl2[3] = {0,0,0},
          sw2[3] = {0,0,0}, slw[3] = {0,0,0};
    float4 cl4, cw4, rl4, dl4;
    #pragma unroll
    for (int dy = -1; dy <= 1; dy++) {
      #pragma unroll
      for (int dx = -1; dx <= 1; dx++) {
        int ni = ci + dy * SW + dx;
        float4 a = L4s[ni];
        float4 wv = W4s[ni];
        sl[0] += a.x;  sl2[0] += a.x * a.x;  sw[0] += wv.x;  sw2[0] += wv.x * wv.x;  slw[0] += a.x * wv.x;
        sl[1] += a.y;  sl2[1] += a.y * a.y;  sw[1] += wv.y;  sw2[1] += wv.y * wv.y;  slw[1] += a.y * wv.y;
        sl[2] += a.z;  sl2[2] += a.z * a.z;  sw[2] += wv.z;  sw2[2] += wv.z * wv.z;  slw[2] += a.z * wv.z;
        if (dy == 0 && dx == 0) { cl4 = a; cw4 = wv; }
        if (dy == 0 && dx == 1) rl4 = a;
        if (dy == 1 && dx == 0) dl4 = a;
      }
    }
    float ds = cl4.w;

    // ---- gt anchor ----
    {
      float g = gt[gidx];
      float trust = (g > 2.0f) ? conf[gidx] * occ[gidx] : 0.f;
      v[0] = trust * fabsf(ds - g);
      v[1] = trust;
    }

    // ---- photometric ----
    {
      float xs = (float)x - ds;
      bool valid = (xs > 0.f) && (xs < (float)(W - 1));
      float cl[3] = {cl4.x, cl4.y, cl4.z};
      float cw[3] = {cw4.x, cw4.y, cw4.z};
      float ssm = 0.f, l1m = 0.f;
      #pragma unroll
      for (int c = 0; c < 3; c++) {
        float mx = sl[c] * (1.f / 9.f), my = sw[c] * (1.f / 9.f);
        float sx = fmaxf(sl2[c] * (1.f / 9.f) - mx * mx, 0.f);
        float sy = fmaxf(sw2[c] * (1.f / 9.f) - my * my, 0.f);
        float sxy = slw[c] * (1.f / 9.f) - mx * my;
        float n  = (2.f * mx * my + 1e-4f) * (2.f * sxy + 9e-4f);
        float dd = (mx * mx + my * my + 1e-4f) * (sx + sy + 9e-4f);
        float ss = (1.f - n / dd) * 0.5f;
        ss = fminf(fmaxf(ss, 0.f), 1.f);
        ssm += ss;
        l1m += fabsf(cl[c] - cw[c]);
      }
      ssm *= (1.f / 3.f); l1m *= (1.f / 3.f);
      float err = 0.85f * ssm + 0.15f * l1m;
      if (valid) { v[2] = err; v[3] = 1.f; }
    }

    // ---- smoothness ----
    if (x < W - 1) {
      float ddx = fabsf(rl4.w - ds);
      float idx = fabsf(rl4.x - cl4.x) + fabsf(rl4.y - cl4.y) + fabsf(rl4.z - cl4.z);
      v[4] = ddx * __expf(-idx * (1.f / 3.f));
    }
    if (y < H - 1) {
      float ddy = fabsf(dl4.w - ds);
      float idy = fabsf(dl4.x - cl4.x) + fabsf(dl4.y - cl4.y) + fabsf(dl4.z - cl4.z);
      v[5] = ddy * __expf(-idy * (1.f / 3.f));
    }
  }

  __shared__ float sm[4][6];
  int wave = threadIdx.x >> 6, lane = threadIdx.x & 63;
  #pragma unroll
  for (int s = 0; s < 6; s++) {
    float r = waveSum(v[s]);
    if (lane == 0) sm[wave][s] = r;
  }
  __syncthreads();
  if (threadIdx.x < 6) {
    float t = sm[0][threadIdx.x] + sm[1][threadIdx.x] +
              sm[2][threadIdx.x] + sm[3][threadIdx.x];
    partialsA[(size_t)threadIdx.x * NBLK + blockIdx.x] = t;
  }
}

// ---------------- fused NCC disparity search, 4 d-groups (R10: single-d pipeline) ----
// grp g covers 12 d's: g0 [-24..-13], g1 [-12..-1], g2 [1..12], g3 [13..24].
// R10 restructure of the d-loop (stall-bound per rocprof: VALUBusy 34%, HBM 3%,
// conflicts 4%):
//   * rgv[29] (the full 29-col RGs window a CH thread touches across all 12 d's)
//     preloaded ONCE into registers via b128 (RGs rows padded 85->88 for 16B
//     alignment). Removes 19 ds_read_b32 per d-pair that used to sit right
//     after a barrier.
//   * single-d iterations with CH ping-pong inside the SAME 3328-float POOL
//     (1664 floats per buffer) -> zero LDS growth, 4 blocks/CU preserved.
//   * one barrier per d (13 regions total, same count as R7), but each region
//     now interleaves vertical(it) [LDS-read chains] with CH(it+1) [pure
//     register VALU + 2 b128 writes] -> stall filler.
// Per-d VALU (25 FMA) and vertical reads (17) are identical to the R7 pair
// version; all LDS access patterns are byte-identical (R9 lesson: do NOT
// change CH layout / thread mapping — interleaved-float2 + 8-row regressed
// 79->115 us via conflicts 2.1M->7.7M and VGPR 60->96).
// LDS 8848 floats = 35392 B -> 4 blocks/CU:
//   @0:    LGs 26x74 (dead after LH) overlaid by RMS float2[16][76] (2432)
//   @2432: RGs 26x88 (85 logical cols, padded) | @4720: POOL 3328 (LH pair /
//          VR pair / CH ping-pong, stride 64)
//   @8048: P1 16x25 | @8448: P2
constexpr int RGST = 88;   // padded RGs row stride (352 B, 16B-aligned rows)

__global__ __launch_bounds__(256, 4) void k_ncc(const float* __restrict__ lg,
                                                const float* __restrict__ rg,
                                                float* __restrict__ bcA,
                                                float* __restrict__ bdA) {
  const int z = blockIdx.z;
  const int b = z >> 2, grp = z & 3;
  const int dmin = (grp == 0) ? -24 : ((grp == 1) ? -12 : ((grp == 2) ? 1 : 13));
  const int x0 = blockIdx.x * 64;
  const int y0 = blockIdx.y * 16;
  const int tid = threadIdx.x;

  __shared__ __align__(16) float SM[8848];
  float* LGs = SM;             // 26 x 74
  float* RMS = SM;             // float2[16][76] row-major (overlays dead LGs)
  float* RGs = SM + 2432;      // 26 x 88 (logical 85 cols)
  float* POOL = SM + 4720;     // 3328
  float* P1 = SM + 8048;       // 16 x 25
  float* P2 = SM + 8448;

  const float* lgb = lg + (size_t)b * (H2 * W2);
  const float* rgb = rg + (size_t)b * (H2 * W2);

  for (int e = tid; e < 26 * 74; e += 256) {
    int r = e / 74, c = e % 74;
    int gy = y0 - 5 + r, gxx = x0 - 5 + c;
    LGs[e] = (gy >= 0 && gy < H2 && gxx >= 0 && gxx < W2) ? lgb[gy * W2 + gxx] : 0.f;
  }
  const int col0RG = x0 - 5 + dmin;
  for (int e = tid; e < 26 * 85; e += 256) {
    int r = e / 85, c = e % 85;
    int gy = y0 - 5 + r, gxx = col0RG + c;
    RGs[r * RGST + c] = (gy >= 0 && gy < H2 && gxx >= 0 && gxx < W2) ? rgb[gy * W2 + gxx] : 0.f;
  }
  __syncthreads();

  // ---- LH pass (horizontal 11-sums of lg, lg^2) + lgc/rgv register caches ----
  const int hg = tid & 7, hr = tid >> 3;
  float lgc[18];
  float rgv[29];
  float* LH1 = POOL;           // 26 x 64
  float* LH2 = POOL + 1664;
  if (hr < 26) {
    #pragma unroll
    for (int k = 0; k < 18; k++) lgc[k] = LGs[hr * 74 + 8 * hg + k];
    // rgv preload: the only RGs data this thread ever needs across all 12 d's
    const float* rp = &RGs[hr * RGST + 8 * hg];
    #pragma unroll
    for (int m = 0; m < 7; m++) {
      float4 q = *(const float4*)(rp + 4 * m);
      rgv[4 * m] = q.x; rgv[4 * m + 1] = q.y; rgv[4 * m + 2] = q.z; rgv[4 * m + 3] = q.w;
    }
    rgv[28] = rp[28];
    float w1[8], w2[8];
    float s1 = 0.f, s2 = 0.f;
    #pragma unroll
    for (int k = 0; k < 11; k++) { s1 += lgc[k]; s2 += lgc[k] * lgc[k]; }
    w1[0] = s1; w2[0] = s2;
    #pragma unroll
    for (int j = 1; j < 8; j++) {
      s1 += lgc[j + 10] - lgc[j - 1];
      s2 += lgc[j + 10] * lgc[j + 10] - lgc[j - 1] * lgc[j - 1];
      w1[j] = s1; w2[j] = s2;
    }
    *(float4*)&LH1[hr * 64 + 8 * hg]     = make_float4(w1[0], w1[1], w1[2], w1[3]);
    *(float4*)&LH1[hr * 64 + 8 * hg + 4] = make_float4(w1[4], w1[5], w1[6], w1[7]);
    *(float4*)&LH2[hr * 64 + 8 * hg]     = make_float4(w2[0], w2[1], w2[2], w2[3]);
    *(float4*)&LH2[hr * 64 + 8 * hg + 4] = make_float4(w2[4], w2[5], w2[6], w2[7]);
  }
  // ---- border column sums (head: global cols 0..23; tail: 456..479) ----
  const bool headT = (grp >= 2) && (x0 == 0);
  const bool tailT = (grp < 2) && (x0 == 448);
  if (headT || tailT) {
    int gcol0 = headT ? 0 : 456;
    for (int e = tid; e < 16 * 24; e += 256) {
      int y = e / 24, i = e % 24;
      int lc = gcol0 + i - col0RG;
      float v1 = 0.f, v2 = 0.f;
      if (lc >= 0 && lc < 85) {
        #pragma unroll
        for (int dy = 0; dy < 11; dy++) {
          float v = RGs[(y + dy) * RGST + lc];
          v1 += v; v2 += v * v;
        }
      }
      P1[y * 25 + i + 1] = v1;
      P2[y * 25 + i + 1] = v2;
    }
  }
  __syncthreads();

  if ((headT || tailT) && tid < 16) {
    int y = tid;
    float s1 = 0.f, s2 = 0.f;
    P1[y * 25] = 0.f; P2[y * 25] = 0.f;
    for (int k = 0; k < 24; k++) {
      s1 += P1[y * 25 + k + 1]; P1[y * 25 + k + 1] = s1;
      s2 += P2[y * 25 + k + 1]; P2[y * 25 + k + 1] = s2;
    }
  }
  const int vx = tid & 63;
  const int vys = (tid >> 6) * 4;
  float lmS[4], lsS[4];   // 121-scaled left mean / std
  {
    float s1 = 0.f, s2 = 0.f;
    #pragma unroll
    for (int dy = 0; dy < 11; dy++) { s1 += LH1[(vys + dy) * 64 + vx]; s2 += LH2[(vys + dy) * 64 + vx]; }
    #pragma unroll
    for (int k = 0; k < 4; k++) {
      if (k) {
        s1 += LH1[(vys + k + 10) * 64 + vx] - LH1[(vys + k - 1) * 64 + vx];
        s2 += LH2[(vys + k + 10) * 64 + vx] - LH2[(vys + k - 1) * 64 + vx];
      }
      float m = s1 * (1.f / 121.f);
      float s = sqrtf(fmaxf(s2 * (1.f / 121.f) - m * m, 1e-8f));
      lmS[k] = m * 121.f;
      lsS[k] = s * 121.f;
    }
  }
  __syncthreads();

  // ---- VR pass: vertical 11-sums of rg, rg^2 (POOL, overwrites LH) ----
  float* VR1 = POOL;           // 16 x 85
  float* VR2 = POOL + 1360;
  if (tid < 170) {
    int c = tid % 85;
    int rr0 = (tid / 85) * 8;
    float s1 = 0.f, s2 = 0.f;
    #pragma unroll
    for (int dy = 0; dy < 11; dy++) {
      float v = RGs[(rr0 + dy) * RGST + c];
      s1 += v; s2 += v * v;
    }
    VR1[rr0 * 85 + c] = s1; VR2[rr0 * 85 + c] = s2;
    #pragma unroll
    for (int k = 1; k < 8; k++) {
      float vin  = RGs[(rr0 + k + 10) * RGST + c];
      float vout = RGs[(rr0 + k - 1) * RGST + c];
      s1 += vin - vout;
      s2 += vin * vin - vout * vout;
      VR1[(rr0 + k) * 85 + c] = s1; VR2[(rr0 + k) * 85 + c] = s2;
    }
  }
  __syncthreads();

  // ---- RV pass fused with moment transform -> RMS float2 (rm, rstd) ----
  {
    int r = tid >> 4, seg = tid & 15;
    int c0 = seg * 5;
    if (c0 < 75) {
      float s1 = 0.f, s2 = 0.f;
      #pragma unroll
      for (int m = 0; m < 11; m++) { s1 += VR1[r * 85 + c0 + m]; s2 += VR2[r * 85 + c0 + m]; }
      #pragma unroll
      for (int j = 0; j < 5; j++) {
        if (j) {
          s1 += VR1[r * 85 + c0 + j + 10] - VR1[r * 85 + c0 + j - 1];
          s2 += VR2[r * 85 + c0 + j + 10] - VR2[r * 85 + c0 + j - 1];
        }
        float rm = s1 * (1.f / 121.f);
        float rstd = sqrtf(fmaxf(s2 * (1.f / 121.f) - rm * rm, 1e-8f));
        *(float2*)&RMS[r * 152 + 2 * (c0 + j)] = make_float2(rm, rstd);
      }
    }
  }
  __syncthreads();

  // ---- d loop: 12 single-d iterations, CH ping-pong, 1 barrier each ----
  const int gx = x0 + vx;
  const bool headL = (grp >= 2) && (gx < 5);
  const bool tailL = (grp < 2) && (gx > 474);
  const bool edgeL = headL || tailL;
  float bnum[4], bden[4], bdd[4];
  #pragma unroll
  for (int k = 0; k < 4; k++) { bnum[k] = -1.f; bden[k] = 1.f; bdd[k] = 0.f; }

  // CH compute for d = dmin + j into dst — pure register VALU from lgc x rgv
  auto chpass = [&](int j, float* dst) {
    if (hr < 26) {
      float ca[8];
      float s = 0.f;
      #pragma unroll
      for (int k = 0; k < 11; k++) s += lgc[k] * rgv[j + k];
      ca[0] = s;
      #pragma unroll
      for (int jj = 1; jj < 8; jj++) {
        s += lgc[jj + 10] * rgv[j + jj + 10] - lgc[jj - 1] * rgv[j + jj - 1];
        ca[jj] = s;
      }
      *(float4*)&dst[hr * 64 + 8 * hg]     = make_float4(ca[0], ca[1], ca[2], ca[3]);
      *(float4*)&dst[hr * 64 + 8 * hg + 4] = make_float4(ca[4], ca[5], ca[6], ca[7]);
    }
  };

  // prologue: CH(0) into buffer 0 (POOL free: VR dead after RMS pass)
  chpass(0, POOL);
  __syncthreads();

  #pragma unroll
  for (int it = 0; it < 12; ++it) {
    float* CHr = POOL + ((it & 1) ? 1664 : 0);
    // issue next d's CH (register FMAs + 2 b128 writes) to overlap with the
    // vertical read chains below — disjoint ping-pong buffer, no hazard
    if (it < 11) chpass(it + 1, POOL + ((it & 1) ? 0 : 1664));
    const int d = dmin + it;
    {
      float a = 0.f;
      #pragma unroll
      for (int dy = 0; dy < 11; dy++) a += CHr[(vys + dy) * 64 + vx];
      #pragma unroll
      for (int k = 0; k < 4; k++) {
        if (k) a += CHr[(vys + k + 10) * 64 + vx] - CHr[(vys + k - 1) * 64 + vx];
        float cs = a;                    // raw 121-sum of lg*rg_shift
        int rvi = vx + it;
        float2 ms = *(const float2*)&RMS[(vys + k) * 152 + 2 * rvi];
        float rm = ms.x, rstd = ms.y;
        if (edgeL) {
          float rs = rm * 121.f;
          float r2 = (rstd * rstd + rm * rm) * 121.f;
          int a_, bI;
          if (headL) { a_ = max(gx - 5 + d, 0); bI = d; }
          else       { a_ = 24 + d; bI = min(gx + 5 + d, 479) - 455; }
          rs -= P1[(vys + k) * 25 + bI] - P1[(vys + k) * 25 + a_];
          r2 -= P2[(vys + k) * 25 + bI] - P2[(vys + k) * 25 + a_];
          rm = rs * (1.f / 121.f);
          rstd = sqrtf(fmaxf(r2 * (1.f / 121.f) - rm * rm, 1e-8f));
        }
        float num = __builtin_fmaf(-lmS[k], rm, cs);
        float den = __builtin_fmaf(lsS[k], rstd, 1.21e-6f);
        if (num * bden[k] > bnum[k] * den) { bnum[k] = num; bden[k] = den; bdd[k] = (float)d; }
      }
    }
    if (it < 11) __syncthreads();
  }

  if (gx < W2) {
    float* bcp = bcA + (size_t)grp * NH + (size_t)b * (H2 * W2);
    float* bdp = bdA + (size_t)grp * NH + (size_t)b * (H2 * W2);
    #pragma unroll
    for (int k = 0; k < 4; k++) {
      size_t o = (size_t)(y0 + vys + k) * W2 + gx;
      bcp[o] = bnum[k] / bden[k];
      bdp[o] = bdd[k];
    }
  }
}

// ------- sign/magnitude: merge 4 d-groups (ascending, strict >), 4 preds each -------
__global__ __launch_bounds__(256) void k_sgm(const float* __restrict__ pred,
                                             const float* __restrict__ bcA,
                                             const float* __restrict__ bdA,
                                             float* __restrict__ partialsB) {
  int tid = blockIdx.x * 256 + threadIdx.x;
  float v6 = 0.f, v7 = 0.f, v8 = 0.f;
  if (tid < NH) {
    int b = tid / (H2 * W2);
    int rem = tid % (H2 * W2);
    int y2 = rem / W2, x2 = rem % W2;
    float bcv = bcA[tid];
    float bdv = bdA[tid];
    #pragma unroll
    for (int g = 1; g < 4; g++) {
      float c = bcA[(size_t)g * NH + tid];
      if (c > bcv) { bcv = c; bdv = bdA[(size_t)g * NH + tid]; }
    }
    if (bcv > 0.3f) {
      float nd = bdv * 2.f;
      float sgn = (nd > 0.f) ? 1.f : ((nd < 0.f) ? -1.f : 0.f);
      const float* pb = pred + (size_t)b * H * W;
      #pragma unroll
      for (int dy = 0; dy < 2; dy++) {
        #pragma unroll
        for (int dx = 0; dx < 2; dx++) {
          float p = pb[(size_t)(2 * y2 + dy) * W + 2 * x2 + dx];
          v6 += fmaxf(-p * sgn, 0.f);
          v7 += bcv * fabsf(p - nd);
        }
      }
      v8 = 4.f;
    }
  }
  __shared__ float sm[4][3];
  int wave = threadIdx.x >> 6, lane = threadIdx.x & 63;
  float r;
  r = waveSum(v6); if (lane == 0) sm[wave][0] = r;
  r = waveSum(v7); if (lane == 0) sm[wave][1] = r;
  r = waveSum(v8); if (lane == 0) sm[wave][2] = r;
  __syncthreads();
  if (threadIdx.x < 3) {
    float t = sm[0][threadIdx.x] + sm[1][threadIdx.x] +
              sm[2][threadIdx.x] + sm[3][threadIdx.x];
    partialsB[(size_t)threadIdx.x * NBLK2 + blockIdx.x] = t;
  }
}

// ---------------- final reduction + scalar composition (1024 threads) ----------------
__global__ __launch_bounds__(1024) void k_final(const float* __restrict__ PA,
                                                const float* __restrict__ PB,
                                                float* __restrict__ out) {
  __shared__ float red[9][16];
  int lane = threadIdx.x & 63, wave = threadIdx.x >> 6;
  #pragma unroll
  for (int s = 0; s < 6; s++) {
    float l = 0.f;
    for (int i = threadIdx.x; i < NBLK; i += 1024) l += PA[(size_t)s * NBLK + i];
    l = waveSum(l);
    if (lane == 0) red[s][wave] = l;
  }
  #pragma unroll
  for (int s = 0; s < 3; s++) {
    float l = 0.f;
    for (int i = threadIdx.x; i < NBLK2; i += 1024) l += PB[(size_t)s * NBLK2 + i];
    l = waveSum(l);
    if (lane == 0) red[6 + s][wave] = l;
  }
  __syncthreads();
  if (threadIdx.x == 0) {
    float a[9];
    #pragma unroll
    for (int s = 0; s < 9; s++) {
      float t = 0.f;
      #pragma unroll
      for (int q = 0; q < 16; q++) t += red[s][q];
      a[s] = t;
    }
    float gtl = a[0] / fmaxf(a[1], 1.f);
    float ph  = a[2] / fmaxf(a[3], 1.f);
    float n   = fmaxf(a[8], 1.f);
    float smv = 0.3f * (a[6] / n) + 0.7f * (a[7] / n);
    float smo = a[4] * (1.f / ((float)B * H * (W - 1)))
              + a[5] * (1.f / ((float)B * (H - 1) * W));
    out[0] = gtl + ph + 0.5f * smv + 0.1f * smo;
  }
}

extern "C" void kernel_launch(void* const* d_in, const int* in_sizes, int n_in,
                              void* d_out, int out_size, void* d_ws, size_t ws_size,
                              hipStream_t stream) {
  const float* pred  = (const float*)d_in[0];
  const float* gt    = (const float*)d_in[1];
  const float* conf  = (const float*)d_in[2];
  const float* occ   = (const float*)d_in[3];
  const float* left  = (const float*)d_in[4];
  const float* right = (const float*)d_in[5];
  float* out = (float*)d_out;

  float* ws = (float*)d_ws;
  float* lg  = ws;
  float* rg  = ws + (size_t)NH;
  float* bcA = ws + 2 * (size_t)NH;                  // 4 * NH
  float* bdA = ws + 6 * (size_t)NH;                  // 4 * NH
  float* partialsA = ws + 10 * (size_t)NH;           // 6 * NBLK
  float* partialsB = partialsA + 6 * (size_t)NBLK;   // 3 * NBLK2

  k_pix<<<NBLK, 256, 0, stream>>>(pred, gt, conf, occ, left, right,
                                  lg, rg, partialsA);

  dim3 nccGrid(8, 17, 16);   // x-tiles, y-tiles, batch*4 d-groups
  k_ncc<<<nccGrid, 256, 0, stream>>>(lg, rg, bcA, bdA);

  k_sgm<<<NBLK2, 256, 0, stream>>>(pred, bcA, bdA, partialsB);

  k_final<<<1, 1024, 0, stream>>>(partialsA, partialsB, out);
}